// Round 3
// baseline (931.416 us; speedup 1.0000x reference)
//
#include <hip/hip_runtime.h>
#include <math.h>

#define BB 64
#define CC 2048
#define MM 196
#define DD 256
#define NTOT (BB * MM)  // 12544

typedef __attribute__((ext_vector_type(8))) short short8;
typedef __attribute__((ext_vector_type(4))) short short4v;
typedef __attribute__((ext_vector_type(4))) unsigned short ushort4v;
typedef __attribute__((ext_vector_type(4))) float f32x4;

__device__ __forceinline__ unsigned short bf16_rne(float f) {
  unsigned int u = __float_as_uint(f);
  unsigned int r = u + 0x7FFFu + ((u >> 16) & 1u);
  return (unsigned short)(r >> 16);
}

// ---------------------------------------------------------------------------
// K0: prep — split W into bf16 hi/lo (wh+wl), precompute BN scale/shift.
// (R0-proven verbatim)
// ---------------------------------------------------------------------------
__global__ __launch_bounds__(256) void k_prep(
    const float* __restrict__ w, const float* __restrict__ gamma,
    const float* __restrict__ beta, const float* __restrict__ rmean,
    const float* __restrict__ rvar, unsigned short* __restrict__ wh,
    unsigned short* __restrict__ wl, float* __restrict__ sclv,
    float* __restrict__ sftv) {
  const int e0 = (blockIdx.x * 256 + threadIdx.x) * 4;
  f32x4 v = *(const f32x4*)(w + e0);
  ushort4v h, l;
#pragma unroll
  for (int i = 0; i < 4; ++i) {
    unsigned short hb = bf16_rne(v[i]);
    float hf = __uint_as_float((unsigned int)hb << 16);
    h[i] = hb;
    l[i] = bf16_rne(v[i] - hf);
  }
  *(ushort4v*)(wh + e0) = h;
  *(ushort4v*)(wl + e0) = l;
  if (blockIdx.x == 0 && threadIdx.x < DD) {
    int d = threadIdx.x;
    float s = gamma[d] / sqrtf(rvar[d] + 1e-5f);
    sclv[d] = s;
    sftv[d] = beta[d] - rmean[d] * s;
  }
}

// ---------------------------------------------------------------------------
// K1: conv+BN+ReLU via bf16 split-3 MFMA (R0-proven verbatim, 142 us).
// ---------------------------------------------------------------------------
__global__ __launch_bounds__(256, 2) void k_conv(
    const float* __restrict__ x, const unsigned short* __restrict__ wh,
    const unsigned short* __restrict__ wl, const float* __restrict__ sclv,
    const float* __restrict__ sftv, float* __restrict__ yt) {
  const int tid = threadIdx.x;
  const int wid = tid >> 6, lane = tid & 63;
  const int quad = lane >> 4, l16 = lane & 15;
  const int n0 = blockIdx.x * 64;

  __shared__ unsigned short Xh[64][36];
  __shared__ unsigned short Xl[64][36];

  f32x4 acc[4][4];
#pragma unroll
  for (int i = 0; i < 4; ++i)
#pragma unroll
    for (int j = 0; j < 4; ++j) acc[i][j] = (f32x4)0.f;

  const int nX = tid & 63, kq = tid >> 6;
  const int gn = n0 + nX;
  const int bX = gn / MM, mX = gn - bX * MM;
  const float* xp = x + (size_t)bX * CC * MM + mX;

  float xr[8];
#pragma unroll
  for (int p = 0; p < 8; ++p) xr[p] = xp[(size_t)(kq * 8 + p) * MM];

  size_t aoff[4];
#pragma unroll
  for (int ds = 0; ds < 4; ++ds)
    aoff[ds] = (size_t)(wid * 64 + ds * 16 + l16) * CC + quad * 8;

  short8 Ah[4], Al[4], Ah2[4], Al2[4];
#pragma unroll
  for (int ds = 0; ds < 4; ++ds) {
    Ah[ds] = *(const short8*)(wh + aoff[ds]);
    Al[ds] = *(const short8*)(wl + aoff[ds]);
  }

  for (int c = 0; c < 64; ++c) {
    const int k0 = c * 32;
    __syncthreads();
    {
      ushort4v h0, h1, l0, l1;
#pragma unroll
      for (int p = 0; p < 4; ++p) {
        unsigned short hb = bf16_rne(xr[p]);
        float hf = __uint_as_float((unsigned int)hb << 16);
        h0[p] = hb;
        l0[p] = bf16_rne(xr[p] - hf);
      }
#pragma unroll
      for (int p = 0; p < 4; ++p) {
        unsigned short hb = bf16_rne(xr[4 + p]);
        float hf = __uint_as_float((unsigned int)hb << 16);
        h1[p] = hb;
        l1[p] = bf16_rne(xr[4 + p] - hf);
      }
      *(ushort4v*)&Xh[nX][kq * 8] = h0;
      *(ushort4v*)&Xh[nX][kq * 8 + 4] = h1;
      *(ushort4v*)&Xl[nX][kq * 8] = l0;
      *(ushort4v*)&Xl[nX][kq * 8 + 4] = l1;
    }
    __syncthreads();
    if (c < 63) {
#pragma unroll
      for (int p = 0; p < 8; ++p)
        xr[p] = xp[(size_t)(k0 + 32 + kq * 8 + p) * MM];
#pragma unroll
      for (int ds = 0; ds < 4; ++ds) {
        Ah2[ds] = *(const short8*)(wh + aoff[ds] + k0 + 32);
        Al2[ds] = *(const short8*)(wl + aoff[ds] + k0 + 32);
      }
    }
#pragma unroll
    for (int ns = 0; ns < 4; ++ns) {
      const unsigned short* bp = &Xh[ns * 16 + l16][quad * 8];
      short4v b0 = *(const short4v*)bp;
      short4v b1 = *(const short4v*)(bp + 4);
      short8 Bh = __builtin_shufflevector(b0, b1, 0, 1, 2, 3, 4, 5, 6, 7);
      const unsigned short* bq = &Xl[ns * 16 + l16][quad * 8];
      short4v c0 = *(const short4v*)bq;
      short4v c1 = *(const short4v*)(bq + 4);
      short8 Bl = __builtin_shufflevector(c0, c1, 0, 1, 2, 3, 4, 5, 6, 7);
#pragma unroll
      for (int ds = 0; ds < 4; ++ds) {
        acc[ds][ns] = __builtin_amdgcn_mfma_f32_16x16x32_bf16(
            Ah[ds], Bh, acc[ds][ns], 0, 0, 0);
        acc[ds][ns] = __builtin_amdgcn_mfma_f32_16x16x32_bf16(
            Ah[ds], Bl, acc[ds][ns], 0, 0, 0);
        acc[ds][ns] = __builtin_amdgcn_mfma_f32_16x16x32_bf16(
            Al[ds], Bh, acc[ds][ns], 0, 0, 0);
      }
    }
#pragma unroll
    for (int ds = 0; ds < 4; ++ds) {
      Ah[ds] = Ah2[ds];
      Al[ds] = Al2[ds];
    }
  }

#pragma unroll
  for (int ds = 0; ds < 4; ++ds) {
    const int dbase = wid * 64 + ds * 16 + quad * 4;
    f32x4 s4 = *(const f32x4*)(sclv + dbase);
    f32x4 f4 = *(const f32x4*)(sftv + dbase);
#pragma unroll
    for (int ns = 0; ns < 4; ++ns) {
      const int n = n0 + ns * 16 + l16;
      const int b = n / MM, m = n - b * MM;
      f32x4 o;
#pragma unroll
      for (int r = 0; r < 4; ++r) {
        float v = fmaf(acc[ds][ns][r], s4[r], f4[r]);
        o[r] = v > 0.f ? v : 0.f;
      }
      *(f32x4*)(yt + ((size_t)b * MM + m) * DD + dbase) = o;
    }
  }
}

// ---------------------------------------------------------------------------
// K2: per-(b,d) mean over m in fp64 (R0-proven verbatim).
// ---------------------------------------------------------------------------
__global__ __launch_bounds__(256) void k_means(const float* __restrict__ yt,
                                               double* __restrict__ mean) {
  const int b = blockIdx.x;
  const int d = threadIdx.x;
  const float* p = yt + (size_t)b * MM * DD + d;
  double s0 = 0, s1 = 0, s2 = 0, s3 = 0;
  for (int m = 0; m < MM; m += 4) {
    s0 += (double)p[(size_t)(m + 0) * DD];
    s1 += (double)p[(size_t)(m + 1) * DD];
    s2 += (double)p[(size_t)(m + 2) * DD];
    s3 += (double)p[(size_t)(m + 3) * DD];
  }
  mean[b * DD + d] = (s0 + s1 + s2 + s3) * (1.0 / MM);
}

// ---------------------------------------------------------------------------
// K3: cov[b] = (Y-mu)(Y-mu)^T / M + eps*I  in fp64, lower tiles mirrored
// (R4-proven VALU version, verbatim).
// ---------------------------------------------------------------------------
__global__ __launch_bounds__(256) void k_cov(const float* __restrict__ yt,
                                             const double* __restrict__ mean,
                                             double* __restrict__ cov) {
  const int b = blockIdx.x;
  const int t = blockIdx.y;
  const int ti = (t < 1) ? 0 : (t < 3) ? 1 : (t < 6) ? 2 : 3;
  const int tj = t - (ti * (ti + 1)) / 2;
  const int i0 = ti * 64, j0 = tj * 64;
  const int tid = threadIdx.x;
  const int tx = tid & 15, ty = tid >> 4;

  __shared__ double As[32][66];
  __shared__ double Bs[32][66];

  double acc[4][4];
#pragma unroll
  for (int i = 0; i < 4; ++i)
#pragma unroll
    for (int j = 0; j < 4; ++j) acc[i][j] = 0.0;

  const int dl = tid & 63, kl = tid >> 6;
  const double mA = mean[b * DD + i0 + dl];
  const double mB = mean[b * DD + j0 + dl];
  const float* ybase = yt + (size_t)b * MM * DD;

  for (int k0 = 0; k0 < MM; k0 += 32) {
    __syncthreads();
#pragma unroll
    for (int p = 0; p < 8; ++p) {
      int k = kl + p * 4;
      int m = k0 + k;
      double av = 0.0, bv = 0.0;
      if (m < MM) {
        av = (double)ybase[(size_t)m * DD + i0 + dl] - mA;
        bv = (double)ybase[(size_t)m * DD + j0 + dl] - mB;
      }
      As[k][dl] = av;
      Bs[k][dl] = bv;
    }
    __syncthreads();
#pragma unroll
    for (int k = 0; k < 32; ++k) {
      double a[4], bv[4];
#pragma unroll
      for (int i = 0; i < 4; ++i) a[i] = As[k][ty * 4 + i];
#pragma unroll
      for (int j = 0; j < 4; ++j) bv[j] = Bs[k][tx * 4 + j];
#pragma unroll
      for (int i = 0; i < 4; ++i)
#pragma unroll
        for (int j = 0; j < 4; ++j) acc[i][j] = fma(a[i], bv[j], acc[i][j]);
    }
  }

  double* cb = cov + (size_t)b * DD * DD;
#pragma unroll
  for (int i = 0; i < 4; ++i) {
#pragma unroll
    for (int j = 0; j < 4; ++j) {
      int gi = i0 + ty * 4 + i, gj = j0 + tx * 4 + j;
      double v = acc[i][j] * (1.0 / MM);
      if (gi == gj) v += 1e-6;
      cb[(size_t)gi * DD + gj] = v;
      if (ti != tj) cb[(size_t)gj * DD + gi] = v;
    }
  }
}

// ---------------------------------------------------------------------------
// K4: per-batch right-looking blocked Cholesky (panel 32) + triuvec output,
// one block per batch, __syncthreads only.  Per-element FMA chains are
// bit-identical to the proven k_panel2 lookahead chain (each tile receives
// panel updates in ascending panel order; each update is a 32-length fma
// chain accumulated in a register then subtracted once; factor/trsm code
// is k_panel2 verbatim).  Upper-triangle staleness is never read.
// ---------------------------------------------------------------------------
__global__ __launch_bounds__(256) void k_chol(double* __restrict__ cov,
                                              float* __restrict__ out) {
  const int b = blockIdx.x;
  const int tid = threadIdx.x;
  double* A = cov + (size_t)b * DD * DD;

  __shared__ double Lb[256][33];   // 67,584 B (panel rows j0..255)
  __shared__ double L11s[32][33];  //  8,448 B
  __shared__ double rpivs[32];
  float* Sf = (float*)&Lb[0][0];  // out-phase alias (64x65 floats)

  for (int kb = 0; kb < 8; ++kb) {
    const int j0 = kb * 32;
    const int R = DD - j0;
    __syncthreads();  // protect Lb from previous step's readers
    // stage panel columns [j0,j0+32), rows [j0,256)  (already fully updated)
    for (int e = tid; e < R * 32; e += 256) {
      int r = e >> 5, c = e & 31;
      Lb[r][c] = A[(size_t)(j0 + r) * DD + j0 + c];
    }
    __syncthreads();

    // 32x32 factor on wave-0 lanes (k_panel2-proven shuffle chain)
    if (tid < 32) {
      double r[32];
#pragma unroll
      for (int k = 0; k < 32; ++k) r[k] = Lb[tid][k];
      double rpkeep = 0.0;
#pragma unroll
      for (int j = 0; j < 32; ++j) {
        double dj = __shfl(r[j], j);
        double piv = sqrt(dj);
        double rp = 1.0 / piv;
        if (tid == j) {
          r[j] = piv;
          rpkeep = rp;
        } else {
          r[j] = r[j] * rp;
        }
        double lij = r[j];
#pragma unroll
        for (int k = j + 1; k < 32; ++k) {
          double ck = __shfl(lij, k);
          r[k] -= lij * ck;
        }
      }
#pragma unroll
      for (int k = 0; k < 32; ++k) L11s[tid][k] = (k <= tid) ? r[k] : 0.0;
      rpivs[tid] = rpkeep;
#pragma unroll
      for (int k = 0; k < 32; ++k)
        if (k <= tid) A[(size_t)(j0 + tid) * DD + j0 + k] = r[k];
    }
    __syncthreads();

    // trsm rows j0+32..255 (k_panel2-proven, row-per-thread)
    if (tid >= 32 && tid < R) {
      double q[32];
#pragma unroll
      for (int k = 0; k < 32; ++k) q[k] = Lb[tid][k];
#pragma unroll
      for (int j = 0; j < 32; ++j) {
        double s = q[j];
#pragma unroll
        for (int k = 0; k < 32; ++k)
          if (k < j) s -= q[k] * L11s[j][k];
        q[j] = s * rpivs[j];
      }
      double* dst = &A[(size_t)(j0 + tid) * DD + j0];
#pragma unroll
      for (int k = 0; k < 32; ++k) {
        dst[k] = q[k];
        Lb[tid][k] = q[k];  // keep L rows in LDS for the trailing update
      }
    }
    __syncthreads();

    // trailing: A[o.., o..] -= Lpanel(kb) * Lpanel(kb)^T  (lower only)
    const int o = j0 + 32;
    const int S = DD - o;
    if (S > 0) {
      const int nt = (S + 63) / 64;
      const int ntiles = nt * (nt + 1) / 2;
      const int txl = tid & 15, tyl = tid >> 4;
      const int bi = tyl * 4, bj = txl * 4;
      for (int tt = 0; tt < ntiles; ++tt) {
        int tI = 0, tJ = tt;
        while (tJ > tI) {
          tJ -= (tI + 1);
          tI++;
        }
        const int i0 = tI * 64, jj0 = tJ * 64;

        int rA[4], rB[4];
        bool va[4], vb[4];
#pragma unroll
        for (int i = 0; i < 4; ++i) {
          int g = i0 + bi + i;
          va[i] = g < S;
          rA[i] = 32 + (va[i] ? g : 0);
          int h = jj0 + bj + i;
          vb[i] = h < S;
          rB[i] = 32 + (vb[i] ? h : 0);
        }

        double s[4][4];
#pragma unroll
        for (int i = 0; i < 4; ++i)
#pragma unroll
          for (int j = 0; j < 4; ++j) s[i][j] = 0.0;

#pragma unroll
        for (int k = 0; k < 32; ++k) {
          double a[4], bv[4];
#pragma unroll
          for (int i = 0; i < 4; ++i) a[i] = va[i] ? Lb[rA[i]][k] : 0.0;
#pragma unroll
          for (int j = 0; j < 4; ++j) bv[j] = vb[j] ? Lb[rB[j]][k] : 0.0;
#pragma unroll
          for (int i = 0; i < 4; ++i)
#pragma unroll
            for (int j = 0; j < 4; ++j) s[i][j] = fma(a[i], bv[j], s[i][j]);
        }

#pragma unroll
        for (int i = 0; i < 4; ++i)
#pragma unroll
          for (int j = 0; j < 4; ++j) {
            int gi = i0 + bi + i, gj = jj0 + bj + j;
            if (gi < S && gj < S && gi >= gj)
              A[(size_t)(o + gi) * DD + (o + gj)] -= s[i][j];
          }
      }
    }
  }

  // ---------------- triuvec output (k_out-proven, per-batch) ---------------
  for (int t = 0; t < 10; ++t) {
    int ti = 0, tj = t;
    while (tj >= 4 - ti) {
      tj -= (4 - ti);
      ti++;
    }
    tj += ti;
    __syncthreads();
    for (int e = tid; e < 4096; e += 256) {
      int jj = e >> 6, ii = e & 63;
      Sf[jj * 65 + ii] = (float)A[(size_t)(tj * 64 + jj) * DD + ti * 64 + ii];
    }
    __syncthreads();
    for (int e = tid; e < 4096; e += 256) {
      int ii = e >> 6, jj = e & 63;
      int i = ti * 64 + ii, j = tj * 64 + jj;
      if (j < i) continue;
      float v = Sf[jj * 65 + ii];
      if (i == j) v = 2.0f * logf(v);
      int off = i * DD - (i * (i - 1)) / 2 + (j - i);
      out[(size_t)b * 32896 + off] = v;
    }
  }
}

extern "C" void kernel_launch(void* const* d_in, const int* in_sizes, int n_in,
                              void* d_out, int out_size, void* d_ws,
                              size_t ws_size, hipStream_t stream) {
  const float* x = (const float*)d_in[0];
  const float* w = (const float*)d_in[1];
  const float* gamma = (const float*)d_in[2];
  const float* beta = (const float*)d_in[3];
  const float* rmean = (const float*)d_in[4];
  const float* rvar = (const float*)d_in[5];
  float* out = (float*)d_out;

  char* ws = (char*)d_ws;
  float* yt = (float*)ws;                           // 12,845,056 B
  double* mean = (double*)(ws + 12845056);          //    131,072 B
  double* cov = (double*)(ws + 12845056 + 131072);  // 33,554,432 B
  // alias W-prep buffers into cov (consumed by k_conv before cov is written)
  unsigned short* wh = (unsigned short*)cov;  // 1,048,576 B
  unsigned short* wl = wh + (DD * CC);        // 1,048,576 B
  float* sclv = (float*)(wl + (DD * CC));     //     1,024 B
  float* sftv = sclv + DD;                    //     1,024 B

  k_prep<<<512, 256, 0, stream>>>(w, gamma, beta, rmean, rvar, wh, wl, sclv,
                                  sftv);
  k_conv<<<NTOT / 64, 256, 0, stream>>>(x, wh, wl, sclv, sftv, yt);
  k_means<<<BB, 256, 0, stream>>>(yt, mean);
  k_cov<<<dim3(BB, 10), 256, 0, stream>>>(yt, mean, cov);
  k_chol<<<BB, 256, 0, stream>>>(cov, out);
}

// Round 4
// 639.153 us; speedup vs baseline: 1.4573x; 1.4573x over previous
//
#include <hip/hip_runtime.h>
#include <math.h>

#define BB 64
#define CC 2048
#define MM 196
#define DD 256
#define NTOT (BB * MM)  // 12544

typedef __attribute__((ext_vector_type(8))) short short8;
typedef __attribute__((ext_vector_type(4))) short short4v;
typedef __attribute__((ext_vector_type(4))) unsigned short ushort4v;
typedef __attribute__((ext_vector_type(4))) float f32x4;

__device__ __forceinline__ unsigned short bf16_rne(float f) {
  unsigned int u = __float_as_uint(f);
  unsigned int r = u + 0x7FFFu + ((u >> 16) & 1u);
  return (unsigned short)(r >> 16);
}

// ---------------------------------------------------------------------------
// K0: prep — split W into bf16 hi/lo (wh+wl), precompute BN scale/shift.
// (R0-proven verbatim)
// ---------------------------------------------------------------------------
__global__ __launch_bounds__(256) void k_prep(
    const float* __restrict__ w, const float* __restrict__ gamma,
    const float* __restrict__ beta, const float* __restrict__ rmean,
    const float* __restrict__ rvar, unsigned short* __restrict__ wh,
    unsigned short* __restrict__ wl, float* __restrict__ sclv,
    float* __restrict__ sftv) {
  const int e0 = (blockIdx.x * 256 + threadIdx.x) * 4;
  f32x4 v = *(const f32x4*)(w + e0);
  ushort4v h, l;
#pragma unroll
  for (int i = 0; i < 4; ++i) {
    unsigned short hb = bf16_rne(v[i]);
    float hf = __uint_as_float((unsigned int)hb << 16);
    h[i] = hb;
    l[i] = bf16_rne(v[i] - hf);
  }
  *(ushort4v*)(wh + e0) = h;
  *(ushort4v*)(wl + e0) = l;
  if (blockIdx.x == 0 && threadIdx.x < DD) {
    int d = threadIdx.x;
    float s = gamma[d] / sqrtf(rvar[d] + 1e-5f);
    sclv[d] = s;
    sftv[d] = beta[d] - rmean[d] * s;
  }
}

// ---------------------------------------------------------------------------
// K1: conv+BN+ReLU via bf16 split-3 MFMA (R0-proven verbatim, 142 us).
// ---------------------------------------------------------------------------
__global__ __launch_bounds__(256, 2) void k_conv(
    const float* __restrict__ x, const unsigned short* __restrict__ wh,
    const unsigned short* __restrict__ wl, const float* __restrict__ sclv,
    const float* __restrict__ sftv, float* __restrict__ yt) {
  const int tid = threadIdx.x;
  const int wid = tid >> 6, lane = tid & 63;
  const int quad = lane >> 4, l16 = lane & 15;
  const int n0 = blockIdx.x * 64;

  __shared__ unsigned short Xh[64][36];
  __shared__ unsigned short Xl[64][36];

  f32x4 acc[4][4];
#pragma unroll
  for (int i = 0; i < 4; ++i)
#pragma unroll
    for (int j = 0; j < 4; ++j) acc[i][j] = (f32x4)0.f;

  const int nX = tid & 63, kq = tid >> 6;
  const int gn = n0 + nX;
  const int bX = gn / MM, mX = gn - bX * MM;
  const float* xp = x + (size_t)bX * CC * MM + mX;

  float xr[8];
#pragma unroll
  for (int p = 0; p < 8; ++p) xr[p] = xp[(size_t)(kq * 8 + p) * MM];

  size_t aoff[4];
#pragma unroll
  for (int ds = 0; ds < 4; ++ds)
    aoff[ds] = (size_t)(wid * 64 + ds * 16 + l16) * CC + quad * 8;

  short8 Ah[4], Al[4], Ah2[4], Al2[4];
#pragma unroll
  for (int ds = 0; ds < 4; ++ds) {
    Ah[ds] = *(const short8*)(wh + aoff[ds]);
    Al[ds] = *(const short8*)(wl + aoff[ds]);
  }

  for (int c = 0; c < 64; ++c) {
    const int k0 = c * 32;
    __syncthreads();
    {
      ushort4v h0, h1, l0, l1;
#pragma unroll
      for (int p = 0; p < 4; ++p) {
        unsigned short hb = bf16_rne(xr[p]);
        float hf = __uint_as_float((unsigned int)hb << 16);
        h0[p] = hb;
        l0[p] = bf16_rne(xr[p] - hf);
      }
#pragma unroll
      for (int p = 0; p < 4; ++p) {
        unsigned short hb = bf16_rne(xr[4 + p]);
        float hf = __uint_as_float((unsigned int)hb << 16);
        h1[p] = hb;
        l1[p] = bf16_rne(xr[4 + p] - hf);
      }
      *(ushort4v*)&Xh[nX][kq * 8] = h0;
      *(ushort4v*)&Xh[nX][kq * 8 + 4] = h1;
      *(ushort4v*)&Xl[nX][kq * 8] = l0;
      *(ushort4v*)&Xl[nX][kq * 8 + 4] = l1;
    }
    __syncthreads();
    if (c < 63) {
#pragma unroll
      for (int p = 0; p < 8; ++p)
        xr[p] = xp[(size_t)(k0 + 32 + kq * 8 + p) * MM];
#pragma unroll
      for (int ds = 0; ds < 4; ++ds) {
        Ah2[ds] = *(const short8*)(wh + aoff[ds] + k0 + 32);
        Al2[ds] = *(const short8*)(wl + aoff[ds] + k0 + 32);
      }
    }
#pragma unroll
    for (int ns = 0; ns < 4; ++ns) {
      const unsigned short* bp = &Xh[ns * 16 + l16][quad * 8];
      short4v b0 = *(const short4v*)bp;
      short4v b1 = *(const short4v*)(bp + 4);
      short8 Bh = __builtin_shufflevector(b0, b1, 0, 1, 2, 3, 4, 5, 6, 7);
      const unsigned short* bq = &Xl[ns * 16 + l16][quad * 8];
      short4v c0 = *(const short4v*)bq;
      short4v c1 = *(const short4v*)(bq + 4);
      short8 Bl = __builtin_shufflevector(c0, c1, 0, 1, 2, 3, 4, 5, 6, 7);
#pragma unroll
      for (int ds = 0; ds < 4; ++ds) {
        acc[ds][ns] = __builtin_amdgcn_mfma_f32_16x16x32_bf16(
            Ah[ds], Bh, acc[ds][ns], 0, 0, 0);
        acc[ds][ns] = __builtin_amdgcn_mfma_f32_16x16x32_bf16(
            Ah[ds], Bl, acc[ds][ns], 0, 0, 0);
        acc[ds][ns] = __builtin_amdgcn_mfma_f32_16x16x32_bf16(
            Al[ds], Bh, acc[ds][ns], 0, 0, 0);
      }
    }
#pragma unroll
    for (int ds = 0; ds < 4; ++ds) {
      Ah[ds] = Ah2[ds];
      Al[ds] = Al2[ds];
    }
  }

#pragma unroll
  for (int ds = 0; ds < 4; ++ds) {
    const int dbase = wid * 64 + ds * 16 + quad * 4;
    f32x4 s4 = *(const f32x4*)(sclv + dbase);
    f32x4 f4 = *(const f32x4*)(sftv + dbase);
#pragma unroll
    for (int ns = 0; ns < 4; ++ns) {
      const int n = n0 + ns * 16 + l16;
      const int b = n / MM, m = n - b * MM;
      f32x4 o;
#pragma unroll
      for (int r = 0; r < 4; ++r) {
        float v = fmaf(acc[ds][ns][r], s4[r], f4[r]);
        o[r] = v > 0.f ? v : 0.f;
      }
      *(f32x4*)(yt + ((size_t)b * MM + m) * DD + dbase) = o;
    }
  }
}

// ---------------------------------------------------------------------------
// K2: per-(b,d) mean over m in fp64 (R0-proven verbatim).
// ---------------------------------------------------------------------------
__global__ __launch_bounds__(256) void k_means(const float* __restrict__ yt,
                                               double* __restrict__ mean) {
  const int b = blockIdx.x;
  const int d = threadIdx.x;
  const float* p = yt + (size_t)b * MM * DD + d;
  double s0 = 0, s1 = 0, s2 = 0, s3 = 0;
  for (int m = 0; m < MM; m += 4) {
    s0 += (double)p[(size_t)(m + 0) * DD];
    s1 += (double)p[(size_t)(m + 1) * DD];
    s2 += (double)p[(size_t)(m + 2) * DD];
    s3 += (double)p[(size_t)(m + 3) * DD];
  }
  mean[b * DD + d] = (s0 + s1 + s2 + s3) * (1.0 / MM);
}

// ---------------------------------------------------------------------------
// K3: cov[b] = (Y-mu)(Y-mu)^T / M + eps*I  in fp64 (R0-proven verbatim).
// ---------------------------------------------------------------------------
__global__ __launch_bounds__(256) void k_cov(const float* __restrict__ yt,
                                             const double* __restrict__ mean,
                                             double* __restrict__ cov) {
  const int b = blockIdx.x;
  const int t = blockIdx.y;
  const int ti = (t < 1) ? 0 : (t < 3) ? 1 : (t < 6) ? 2 : 3;
  const int tj = t - (ti * (ti + 1)) / 2;
  const int i0 = ti * 64, j0 = tj * 64;
  const int tid = threadIdx.x;
  const int tx = tid & 15, ty = tid >> 4;

  __shared__ double As[32][66];
  __shared__ double Bs[32][66];

  double acc[4][4];
#pragma unroll
  for (int i = 0; i < 4; ++i)
#pragma unroll
    for (int j = 0; j < 4; ++j) acc[i][j] = 0.0;

  const int dl = tid & 63, kl = tid >> 6;
  const double mA = mean[b * DD + i0 + dl];
  const double mB = mean[b * DD + j0 + dl];
  const float* ybase = yt + (size_t)b * MM * DD;

  for (int k0 = 0; k0 < MM; k0 += 32) {
    __syncthreads();
#pragma unroll
    for (int p = 0; p < 8; ++p) {
      int k = kl + p * 4;
      int m = k0 + k;
      double av = 0.0, bv = 0.0;
      if (m < MM) {
        av = (double)ybase[(size_t)m * DD + i0 + dl] - mA;
        bv = (double)ybase[(size_t)m * DD + j0 + dl] - mB;
      }
      As[k][dl] = av;
      Bs[k][dl] = bv;
    }
    __syncthreads();
#pragma unroll
    for (int k = 0; k < 32; ++k) {
      double a[4], bv[4];
#pragma unroll
      for (int i = 0; i < 4; ++i) a[i] = As[k][ty * 4 + i];
#pragma unroll
      for (int j = 0; j < 4; ++j) bv[j] = Bs[k][tx * 4 + j];
#pragma unroll
      for (int i = 0; i < 4; ++i)
#pragma unroll
        for (int j = 0; j < 4; ++j) acc[i][j] = fma(a[i], bv[j], acc[i][j]);
    }
  }

  double* cb = cov + (size_t)b * DD * DD;
#pragma unroll
  for (int i = 0; i < 4; ++i) {
#pragma unroll
    for (int j = 0; j < 4; ++j) {
      int gi = i0 + ty * 4 + i, gj = j0 + tx * 4 + j;
      double v = acc[i][j] * (1.0 / MM);
      if (gi == gj) v += 1e-6;
      cb[(size_t)gi * DD + gj] = v;
      if (ti != tj) cb[(size_t)gj * DD + gi] = v;
    }
  }
}

// ---------------------------------------------------------------------------
// K4: lookahead Cholesky step kb — same launch structure & op-order as the
// R0-proven k_panel2, but LDS cut 135KB -> 33.8KB: the panel path keeps its
// row in registers (sp[32]) with only LpTop/L11s/rpivs in LDS; the trailing
// path keeps the proven Ea/Eb microkernel.  kb==7's panel block also emits
// the triuvec output for its batch (k_out-proven code), removing a launch.
// ---------------------------------------------------------------------------
__global__ __launch_bounds__(256) void k_panel3(double* __restrict__ cov,
                                                float* __restrict__ out,
                                                int kb) {
  const int b = blockIdx.x;
  double* A = cov + (size_t)b * DD * DD;
  const int j0 = kb * 32;
  const int tid = threadIdx.x;

  __shared__ double sh[4224];  // 33,792 B union

  if (blockIdx.y == 0) {
    double(*LpTop)[33] = (double(*)[33])sh;        // 32x33
    double(*L11s)[33] = (double(*)[33])(sh + 1056);  // 32x33
    double* rpivs = sh + 2112;
    const int R = DD - j0;
    const int pj = j0 - 32;

    // stage this thread's panel row in registers
    double sp[32];
    const double* rowp = A + (size_t)(j0 + tid) * DD;
    if (tid < R) {
#pragma unroll
      for (int c = 0; c < 32; ++c) sp[c] = rowp[j0 + c];
    }

    if (kb > 0) {
      double lp[32];
      if (tid < R) {
#pragma unroll
        for (int c = 0; c < 32; ++c) lp[c] = rowp[pj + c];
      }
      if (tid < 32) {
#pragma unroll
        for (int c = 0; c < 32; ++c) LpTop[tid][c] = lp[c];
      }
      __syncthreads();
      // syrk correction: sp[c] -= <lp, Lp(row j0+c)>
      if (tid < R) {
#pragma unroll
        for (int c = 0; c < 32; ++c) {
          double a = 0.0;
#pragma unroll
          for (int p = 0; p < 32; ++p) a = fma(lp[p], LpTop[c][p], a);
          sp[c] -= a;
        }
      }
    }

    // 32x32 factor on wave-0 lanes (k_panel2-proven shuffle chain)
    if (tid < 32) {
      double rpkeep = 0.0;
#pragma unroll
      for (int j = 0; j < 32; ++j) {
        double dj = __shfl(sp[j], j);
        double piv = sqrt(dj);
        double rp = 1.0 / piv;
        if (tid == j) {
          sp[j] = piv;
          rpkeep = rp;
        } else {
          sp[j] = sp[j] * rp;
        }
        double lij = sp[j];
#pragma unroll
        for (int k = j + 1; k < 32; ++k) {
          double ck = __shfl(lij, k);
          sp[k] -= lij * ck;
        }
      }
#pragma unroll
      for (int k = 0; k < 32; ++k) L11s[tid][k] = (k <= tid) ? sp[k] : 0.0;
      rpivs[tid] = rpkeep;
      for (int k = 0; k <= tid; ++k)
        A[(size_t)(j0 + tid) * DD + j0 + k] = sp[k];
    }
    __syncthreads();

    // trsm rows j0+32..255 (k_panel2-proven, row-per-thread)
    if (tid >= 32 && tid < R) {
#pragma unroll
      for (int j = 0; j < 32; ++j) {
        double s = sp[j];
#pragma unroll
        for (int k = 0; k < 32; ++k)
          if (k < j) s -= sp[k] * L11s[j][k];
        sp[j] = s * rpivs[j];
      }
      double* dst = A + (size_t)(j0 + tid) * DD + j0;
#pragma unroll
      for (int k = 0; k < 32; ++k) dst[k] = sp[k];
    }

    // ---- kb==7: whole factorization done for this batch; emit triuvec ----
    if (kb == 7) {
      float* Sf = (float*)sh;  // 64x65 floats
      __syncthreads();
      for (int t = 0; t < 10; ++t) {
        int ti = 0, tj = t;
        while (tj >= 4 - ti) {
          tj -= (4 - ti);
          ti++;
        }
        tj += ti;
        __syncthreads();
        for (int e = tid; e < 4096; e += 256) {
          int jj = e >> 6, ii = e & 63;
          Sf[jj * 65 + ii] =
              (float)A[(size_t)(tj * 64 + jj) * DD + ti * 64 + ii];
        }
        __syncthreads();
        for (int e = tid; e < 4096; e += 256) {
          int ii = e >> 6, jj = e & 63;
          int i = ti * 64 + ii, j = tj * 64 + jj;
          if (j < i) continue;
          float v = Sf[jj * 65 + ii];
          if (i == j) v = 2.0f * logf(v);
          int off = i * DD - (i * (i - 1)) / 2 + (j - i);
          out[(size_t)b * 32896 + off] = v;
        }
      }
    }
  } else {
    // trailing: apply panel kb-1 to [o,256)^2 (R0-proven verbatim, Ea/Eb)
    const int o = j0 + 32;
    const int S = DD - o;
    const int pj = j0 - 32;
    int tI = 0, tJ = (int)blockIdx.y - 1;
    while (tJ > tI) {
      tJ -= (tI + 1);
      tI++;
    }
    const int i0 = tI * 64, jj0 = tJ * 64;
    const int txl = tid & 15, tyl = tid >> 4;

    double(*Ea)[33] = (double(*)[33])sh;           // 64x33
    double(*Eb)[33] = (double(*)[33])(sh + 2112);  // 64x33

    for (int e = tid; e < 64 * 32; e += 256) {
      int r = e >> 5, c = e & 31;
      Ea[r][c] = (i0 + r < S) ? A[(size_t)(o + i0 + r) * DD + pj + c] : 0.0;
      Eb[r][c] = (jj0 + r < S) ? A[(size_t)(o + jj0 + r) * DD + pj + c] : 0.0;
    }
    __syncthreads();

    double s[4][4];
#pragma unroll
    for (int i = 0; i < 4; ++i)
#pragma unroll
      for (int j = 0; j < 4; ++j) s[i][j] = 0.0;

    const int bi = tyl * 4, bj = txl * 4;
#pragma unroll
    for (int k = 0; k < 32; ++k) {
      double a[4], bv[4];
#pragma unroll
      for (int i = 0; i < 4; ++i) a[i] = Ea[bi + i][k];
#pragma unroll
      for (int j = 0; j < 4; ++j) bv[j] = Eb[bj + j][k];
#pragma unroll
      for (int i = 0; i < 4; ++i)
#pragma unroll
        for (int j = 0; j < 4; ++j) s[i][j] = fma(a[i], bv[j], s[i][j]);
    }

#pragma unroll
    for (int i = 0; i < 4; ++i)
#pragma unroll
      for (int j = 0; j < 4; ++j) {
        int gi = i0 + bi + i, gj = jj0 + bj + j;
        if (gi < S && gj < S && gi >= gj)
          A[(size_t)(o + gi) * DD + (o + gj)] -= s[i][j];
      }
  }
}

extern "C" void kernel_launch(void* const* d_in, const int* in_sizes, int n_in,
                              void* d_out, int out_size, void* d_ws,
                              size_t ws_size, hipStream_t stream) {
  const float* x = (const float*)d_in[0];
  const float* w = (const float*)d_in[1];
  const float* gamma = (const float*)d_in[2];
  const float* beta = (const float*)d_in[3];
  const float* rmean = (const float*)d_in[4];
  const float* rvar = (const float*)d_in[5];
  float* out = (float*)d_out;

  char* ws = (char*)d_ws;
  float* yt = (float*)ws;                           // 12,845,056 B
  double* mean = (double*)(ws + 12845056);          //    131,072 B
  double* cov = (double*)(ws + 12845056 + 131072);  // 33,554,432 B
  // alias W-prep buffers into cov (consumed by k_conv before cov is written)
  unsigned short* wh = (unsigned short*)cov;  // 1,048,576 B
  unsigned short* wl = wh + (DD * CC);        // 1,048,576 B
  float* sclv = (float*)(wl + (DD * CC));     //     1,024 B
  float* sftv = sclv + DD;                    //     1,024 B

  k_prep<<<512, 256, 0, stream>>>(w, gamma, beta, rmean, rvar, wh, wl, sclv,
                                  sftv);
  k_conv<<<NTOT / 64, 256, 0, stream>>>(x, wh, wl, sclv, sftv, yt);
  k_means<<<BB, 256, 0, stream>>>(yt, mean);
  k_cov<<<dim3(BB, 10), 256, 0, stream>>>(yt, mean, cov);
  for (int kb = 0; kb < 8; ++kb) {
    int ntiles = 0;
    if (kb > 0) {
      int S = DD - (kb * 32 + 32);
      if (S > 0) {
        int nt = (S + 63) / 64;
        ntiles = nt * (nt + 1) / 2;
      }
    }
    k_panel3<<<dim3(BB, 1 + ntiles), 256, 0, stream>>>(cov, out, kb);
  }
}